// Round 6
// baseline (483.962 us; speedup 1.0000x reference)
//
#include <hip/hip_runtime.h>
#include <stdint.h>

// ---------------- types & helpers ----------------
typedef __bf16 bf16x8 __attribute__((ext_vector_type(8)));
typedef float f32x4 __attribute__((ext_vector_type(4)));
typedef unsigned int u32x4 __attribute__((ext_vector_type(4)));

static __device__ __forceinline__ unsigned short f2b(float f) {
  unsigned u = __builtin_bit_cast(unsigned, f);
  u = (u + 0x7fffu + ((u >> 16) & 1u)) >> 16;
  return (unsigned short)u;
}

// proper addrspacecast (NOT via uintptr_t — that keeps the flat aperture bits)
__device__ __forceinline__ void gl_lds16(const void* g, void* l) {
  __builtin_amdgcn_global_load_lds(
      (const __attribute__((address_space(1))) void*)g,
      (__attribute__((address_space(3))) void*)l, 16, 0, 0);
}

static __device__ __forceinline__ float gelu_tanh(float x) {
  // 0.5x(1+tanh(c(x+0.044715x^3))) == x*sigmoid(2c(x+0.044715x^3))
  float z = 1.5957691216057308f * (x + 0.044715f * x * x * x);  // 2*c
  float t = __expf(-z);
  return x * __builtin_amdgcn_rcpf(1.0f + t);
}

// ---------------- unified convert kernel ----------------
// block ranges:
//   [0,4096)      x [S,B,D] f32 -> xbf [B,S,D] bf16 (row permute)
//   [4096,5120)   Wq -> wqk[0:1M)
//   [5120,6144)   Wk -> wqk[1M:2M)
//   [6144,7168)   Wv -> wv
//   [7168,8192)   Wo -> wo
//   [8192,12288)  W1 -> w1
//   [12288,16384) W2 -> w2
//   16384         bq -> bqk[0:1024)   (f32 copy)
//   16385         bk -> bqk[1024:2048)
__global__ __launch_bounds__(256) void cvt_all(
    const float* __restrict__ x, unsigned short* __restrict__ xbf,
    const float* __restrict__ Wq, const float* __restrict__ Wk,
    unsigned short* __restrict__ wqk,
    const float* __restrict__ Wv, unsigned short* __restrict__ wv,
    const float* __restrict__ Wo, unsigned short* __restrict__ wo,
    const float* __restrict__ W1, unsigned short* __restrict__ w1,
    const float* __restrict__ W2, unsigned short* __restrict__ w2,
    const float* __restrict__ bq, const float* __restrict__ bk,
    float* __restrict__ bqk) {
  const int blk = blockIdx.x;
  const int tid = threadIdx.x;
  if (blk < 4096) {  // x permute+convert: one token row per block
    int t = blk;  // b-major token: b = t>>11, s = t&2047
    int rin = (t & 2047) * 2 + (t >> 11);
    float4 v = ((const float4*)(x + (size_t)rin * 1024))[tid];
    ((ushort4*)(xbf + (size_t)t * 1024))[tid] =
        make_ushort4(f2b(v.x), f2b(v.y), f2b(v.z), f2b(v.w));
    return;
  }
  if (blk >= 16384) {  // bias concat (f32)
    const float* src = (blk == 16384) ? bq : bk;
    ((float4*)(bqk + (blk - 16384) * 1024))[tid] = ((const float4*)src)[tid];
    return;
  }
  const float* src;
  unsigned short* dst;
  int i;
  if (blk < 5120)       { src = Wq; dst = wqk;           i = (blk - 4096) * 256 + tid; }
  else if (blk < 6144)  { src = Wk; dst = wqk + 1048576; i = (blk - 5120) * 256 + tid; }
  else if (blk < 7168)  { src = Wv; dst = wv;            i = (blk - 6144) * 256 + tid; }
  else if (blk < 8192)  { src = Wo; dst = wo;            i = (blk - 7168) * 256 + tid; }
  else if (blk < 12288) { src = W1; dst = w1;            i = (blk - 8192) * 256 + tid; }
  else                  { src = W2; dst = w2;            i = (blk - 12288) * 256 + tid; }
  float4 v = ((const float4*)src)[i];
  ((ushort4*)dst)[i] = make_ushort4(f2b(v.x), f2b(v.y), f2b(v.z), f2b(v.w));
}

// ---------------- bf16 GEMM: C[M,N] = A[M,K] * Bw[N,K]^T + bias ----------------
// EPI: 0 = bias -> bf16 out, 1 = bias -> f32 out, 2 = bias+gelu -> bf16 out
// RB:  false = bias[col], true = bias[row] (used for the transposed-V gemm)
#define BM 128
#define BN 128
#define BK 32

template <int EPI, bool RB>
__global__ __launch_bounds__(256) void gemm_bt(const unsigned short* __restrict__ A,
                                               const unsigned short* __restrict__ Bw,
                                               const float* __restrict__ bias,
                                               float* __restrict__ Cf,
                                               unsigned short* __restrict__ Cb,
                                               int M, int N, int K) {
  __shared__ unsigned short As[BM * BK];  // 8 KB, chunk-swizzled: chunk ^= (row>>1)&3
  __shared__ unsigned short Bs[BN * BK];  // 8 KB
  const int tid = threadIdx.x;
  const int lane = tid & 63;
  const int w = tid >> 6;
  const int wm = w & 1, wn = w >> 1;
  const int l15 = lane & 15, lg = lane >> 4;
  const int nbn = N / BN;
  const int bm = blockIdx.x / nbn, bn = blockIdx.x % nbn;

  f32x4 acc[4][4];
#pragma unroll
  for (int i = 0; i < 4; ++i)
#pragma unroll
    for (int j = 0; j < 4; ++j) acc[i][j] = (f32x4){0.f, 0.f, 0.f, 0.f};

  for (int k0 = 0; k0 < K; k0 += BK) {
    __syncthreads();
#pragma unroll
    for (int i = 0; i < 2; ++i) {
      int p = i * 256 + tid;
      int row = p >> 2, c = p & 3;
      int gc = c ^ ((row >> 1) & 3);  // pre-swizzled global source (rule 21)
      gl_lds16(A + ((size_t)(bm * BM + row) * K + k0 + gc * 8), (char*)As + p * 16);
      gl_lds16(Bw + ((size_t)(bn * BN + row) * K + k0 + gc * 8), (char*)Bs + p * 16);
    }
    __syncthreads();

    bf16x8 af[4], bfr[4];
#pragma unroll
    for (int mt = 0; mt < 4; ++mt) {
      int row = wm * 64 + mt * 16 + l15;
      int ch = lg ^ ((row >> 1) & 3);
      af[mt] = __builtin_bit_cast(bf16x8, *(const u32x4*)((const char*)As + row * 64 + ch * 16));
    }
#pragma unroll
    for (int nt = 0; nt < 4; ++nt) {
      int row = wn * 64 + nt * 16 + l15;
      int ch = lg ^ ((row >> 1) & 3);
      bfr[nt] = __builtin_bit_cast(bf16x8, *(const u32x4*)((const char*)Bs + row * 64 + ch * 16));
    }
#pragma unroll
    for (int mt = 0; mt < 4; ++mt)
#pragma unroll
      for (int nt = 0; nt < 4; ++nt)
        acc[mt][nt] = __builtin_amdgcn_mfma_f32_16x16x32_bf16(af[mt], bfr[nt], acc[mt][nt], 0, 0, 0);
  }

  // epilogue: C/D layout col = lane&15, row = (lane>>4)*4 + j   [m89]
#pragma unroll
  for (int mt = 0; mt < 4; ++mt) {
    const int rowb = bm * BM + wm * 64 + mt * 16 + lg * 4;
#pragma unroll
    for (int nt = 0; nt < 4; ++nt) {
      int col = bn * BN + wn * 64 + nt * 16 + l15;
      float bc = RB ? 0.f : bias[col];
#pragma unroll
      for (int j = 0; j < 4; ++j) {
        float v = acc[mt][nt][j] + (RB ? bias[rowb + j] : bc);
        if (EPI == 2) v = gelu_tanh(v);
        if (EPI == 1)
          Cf[(size_t)(rowb + j) * N + col] = v;
        else
          Cb[(size_t)(rowb + j) * N + col] = f2b(v);
      }
    }
  }
}

// ---------------- flash attention ----------------
// grid: (qblocks=32, bh=32); 256 threads = 4 waves, each wave 16 q-rows.
// QK bf16 [4096 tok(b-major)][2048] (Q cols 0-1023, K cols 1024-2047);
// Vt bf16 [1024 e][4096 tok(b-major)].
__global__ __launch_bounds__(256) void attn_kernel(const unsigned short* __restrict__ QK,
                                                   const unsigned short* __restrict__ Vt,
                                                   unsigned short* __restrict__ Ob) {
  __shared__ unsigned short Ks[64 * 64];      // [kv][d], chunk ^= (kv&7)
  __shared__ unsigned short Vs[64 * 64];      // [d][kv], chunk ^= (d&7)
  __shared__ unsigned short Ps[4 * 16 * 64];  // per-wave P [m][kv], chunk ^= (m&7)

  const int tid = threadIdx.x;
  const int lane = tid & 63;
  const int w = tid >> 6;
  const int l15 = lane & 15, lg = lane >> 4;
  const int qb = blockIdx.x;
  const int bh = blockIdx.y;
  const int b = bh >> 4, h = bh & 15;

  // Q fragments (A-operand): row = lane&15, k = (lane>>4)*8 (+32 for kh=1)
  const int qs = qb * 64 + w * 16 + l15;
  const unsigned short* qptr = QK + ((size_t)(b * 2048 + qs)) * 2048 + h * 64 + lg * 8;
  bf16x8 qf[2];
  qf[0] = __builtin_bit_cast(bf16x8, *(const u32x4*)qptr);
  qf[1] = __builtin_bit_cast(bf16x8, *(const u32x4*)(qptr + 32));

  f32x4 oacc[4];
#pragma unroll
  for (int i = 0; i < 4; ++i) oacc[i] = (f32x4){0.f, 0.f, 0.f, 0.f};
  float mj[4] = {-1e30f, -1e30f, -1e30f, -1e30f};
  float lj[4] = {0.f, 0.f, 0.f, 0.f};

  unsigned short* Pw = Ps + w * 1024;
  const unsigned short* Kbase = QK + 1024;  // K columns

  for (int kt = 0; kt < 32; ++kt) {
    __syncthreads();
#pragma unroll
    for (int i = 0; i < 2; ++i) {
      int p = i * 256 + tid;
      int row = p >> 3, c = p & 7;
      int gc = c ^ (row & 7);
      // K: row = kv token, contiguous d (row stride 2048)
      gl_lds16(Kbase + ((size_t)(b * 2048 + kt * 64 + row)) * 2048 + h * 64 + gc * 8,
               (char*)Ks + p * 16);
      // V^T: row = d, contiguous kv tokens
      gl_lds16(Vt + ((size_t)(h * 64 + row)) * 4096 + b * 2048 + kt * 64 + gc * 8,
               (char*)Vs + p * 16);
    }
    __syncthreads();

    // S = Q K^T  (per wave: 16 x 64)
    f32x4 sa[4];
#pragma unroll
    for (int i = 0; i < 4; ++i) sa[i] = (f32x4){0.f, 0.f, 0.f, 0.f};
#pragma unroll
    for (int nt = 0; nt < 4; ++nt) {
      int n = nt * 16 + l15;
#pragma unroll
      for (int kh = 0; kh < 2; ++kh) {
        int ch = (kh * 4 + lg) ^ (n & 7);
        bf16x8 kf = __builtin_bit_cast(bf16x8, *(const u32x4*)((const char*)Ks + n * 128 + ch * 16));
        sa[nt] = __builtin_amdgcn_mfma_f32_16x16x32_bf16(qf[kh], kf, sa[nt], 0, 0, 0);
      }
    }

    // online softmax (fp32); rows per lane: m = lg*4+j, cols nt*16+l15
#pragma unroll
    for (int nt = 0; nt < 4; ++nt)
#pragma unroll
      for (int j = 0; j < 4; ++j) sa[nt][j] *= 0.125f;

#pragma unroll
    for (int j = 0; j < 4; ++j) {
      float rm = fmaxf(fmaxf(sa[0][j], sa[1][j]), fmaxf(sa[2][j], sa[3][j]));
#pragma unroll
      for (int d = 1; d < 16; d <<= 1) rm = fmaxf(rm, __shfl_xor(rm, d));
      float mnew = fmaxf(mj[j], rm);
      float corr = __expf(mj[j] - mnew);
      mj[j] = mnew;
      float rs = 0.f;
#pragma unroll
      for (int nt = 0; nt < 4; ++nt) {
        float p = __expf(sa[nt][j] - mnew);
        sa[nt][j] = p;
        rs += p;
      }
#pragma unroll
      for (int d = 1; d < 16; d <<= 1) rs += __shfl_xor(rs, d);
      lj[j] = lj[j] * corr + rs;
#pragma unroll
      for (int dt = 0; dt < 4; ++dt) oacc[dt][j] *= corr;
    }

    // P -> LDS (bf16), swizzled by row m
#pragma unroll
    for (int nt = 0; nt < 4; ++nt)
#pragma unroll
      for (int j = 0; j < 4; ++j) {
        int m = lg * 4 + j;
        int c = nt * 16 + l15;
        int pos = m * 64 + (((c >> 3) ^ (m & 7)) << 3) + (c & 7);
        Pw[pos] = f2b(sa[nt][j]);
      }

    // O += P V : A = P rows (m), B = V^T rows (d) — both b128 swizzled reads
#pragma unroll
    for (int kh = 0; kh < 2; ++kh) {
      int kc = kh * 4 + lg;
      bf16x8 pa = __builtin_bit_cast(
          bf16x8, *(const u32x4*)(Pw + l15 * 64 + ((kc ^ (l15 & 7)) << 3)));
#pragma unroll
      for (int dt = 0; dt < 4; ++dt) {
        int drow = dt * 16 + l15;
        int ch = kc ^ (drow & 7);
        bf16x8 vf = __builtin_bit_cast(bf16x8, *(const u32x4*)((const char*)Vs + drow * 128 + ch * 16));
        oacc[dt] = __builtin_amdgcn_mfma_f32_16x16x32_bf16(pa, vf, oacc[dt], 0, 0, 0);
      }
    }
  }

  // write O (bf16): rows come out as lg*4+j per C/D layout
#pragma unroll
  for (int dt = 0; dt < 4; ++dt)
#pragma unroll
    for (int j = 0; j < 4; ++j) {
      int s = qb * 64 + w * 16 + lg * 4 + j;
      int d = h * 64 + dt * 16 + l15;
      float v = oacc[dt][j] / lj[j];
      Ob[((size_t)(b * 2048 + s)) * 1024 + d] = f2b(v);
    }
}

// ---------------- residual + LayerNorm ----------------
// REMA: remap the A-read row (A is [S,B,D] while t is b-major)
// REMO: remap the output row (out is [S,B,D])
template <bool WB, bool REMA, bool REMO>
__global__ __launch_bounds__(256) void ln_res(const float* __restrict__ A,
                                              const float* __restrict__ Bb,
                                              const float* __restrict__ g,
                                              const float* __restrict__ be,
                                              float* __restrict__ Of,
                                              unsigned short* __restrict__ Ob) {
  const int t = blockIdx.x;  // b-major token
  const int rowA = REMA ? ((t & 2047) * 2 + (t >> 11)) : t;
  const int rowO = REMO ? ((t & 2047) * 2 + (t >> 11)) : t;
  const int tt = threadIdx.x;
  float4 v = ((const float4*)(A + (size_t)rowA * 1024))[tt];
  float4 u = ((const float4*)(Bb + (size_t)t * 1024))[tt];
  v.x += u.x; v.y += u.y; v.z += u.z; v.w += u.w;
  float s = v.x + v.y + v.z + v.w;
  float ss = v.x * v.x + v.y * v.y + v.z * v.z + v.w * v.w;
#pragma unroll
  for (int d = 1; d < 64; d <<= 1) {
    s += __shfl_xor(s, d);
    ss += __shfl_xor(ss, d);
  }
  __shared__ float red[8];
  int wv = tt >> 6, lane = tt & 63;
  if (lane == 0) { red[wv] = s; red[4 + wv] = ss; }
  __syncthreads();
  s = red[0] + red[1] + red[2] + red[3];
  ss = red[4] + red[5] + red[6] + red[7];
  float mu = s * (1.f / 1024.f);
  float var = ss * (1.f / 1024.f) - mu * mu;
  float rstd = rsqrtf(var + 1e-5f);
  float4 gg = ((const float4*)g)[tt];
  float4 bb = ((const float4*)be)[tt];
  float o0 = (v.x - mu) * rstd * gg.x + bb.x;
  float o1 = (v.y - mu) * rstd * gg.y + bb.y;
  float o2 = (v.z - mu) * rstd * gg.z + bb.z;
  float o3 = (v.w - mu) * rstd * gg.w + bb.w;
  ((float4*)(Of + (size_t)rowO * 1024))[tt] = make_float4(o0, o1, o2, o3);
  if (WB) {
    ((ushort4*)(Ob + (size_t)t * 1024))[tt] =
        make_ushort4(f2b(o0), f2b(o1), f2b(o2), f2b(o3));
  }
}

// ---------------- launch ----------------
extern "C" void kernel_launch(void* const* d_in, const int* in_sizes, int n_in,
                              void* d_out, int out_size, void* d_ws, size_t ws_size,
                              hipStream_t stream) {
  const float* x   = (const float*)d_in[0];
  const float* Wq  = (const float*)d_in[1];
  const float* bq  = (const float*)d_in[2];
  const float* Wk  = (const float*)d_in[3];
  const float* bk  = (const float*)d_in[4];
  const float* Wv  = (const float*)d_in[5];
  const float* bv  = (const float*)d_in[6];
  const float* Wo  = (const float*)d_in[7];
  const float* bo  = (const float*)d_in[8];
  const float* W1  = (const float*)d_in[9];
  const float* b1  = (const float*)d_in[10];
  const float* W2  = (const float*)d_in[11];
  const float* b2  = (const float*)d_in[12];
  const float* g1  = (const float*)d_in[13];
  const float* be1 = (const float*)d_in[14];
  const float* g2  = (const float*)d_in[15];
  const float* be2 = (const float*)d_in[16];

  char* ws = (char*)d_ws;
  const size_t MB = 1024ull * 1024ull;
  unsigned short* xbf  = (unsigned short*)(ws + 0);        // 8 MB  [B,S,D] bf16
  unsigned short* wqkb = (unsigned short*)(ws + 8 * MB);   // 4 MB  Wq||Wk [2048][1024]
  unsigned short* wvb  = (unsigned short*)(ws + 12 * MB);  // 2 MB
  unsigned short* wob  = (unsigned short*)(ws + 14 * MB);  // 2 MB
  unsigned short* w1b  = (unsigned short*)(ws + 16 * MB);  // 8 MB
  unsigned short* w2b  = (unsigned short*)(ws + 24 * MB);  // 8 MB
  unsigned short* qkbuf= (unsigned short*)(ws + 32 * MB);  // 16 MB [tok][2048]
  unsigned short* vbufT= (unsigned short*)(ws + 48 * MB);  // 8 MB  [1024][tok] (V^T)
  unsigned short* aobf = (unsigned short*)(ws + 56 * MB);  // 8 MB  [tok][1024]
  unsigned short* y1   = (unsigned short*)(ws + 32 * MB);  // 32 MB, aliases qk/vT/ao (dead)
  float* of32 = (float*)(ws + 64 * MB);                    // 16 MB
  float* y2   = (float*)(ws + 64 * MB);                    // aliases of32 (dead by then)
  float* xn   = (float*)(ws + 80 * MB);                    // 16 MB
  unsigned short* xnbf = (unsigned short*)(ws + 96 * MB);  // 8 MB
  // bqk (2048 f32 = 8 KB) overlaid at start of xn region: written by cvt_all,
  // read only by the QK GEMM, dead before LN1 writes xn.
  float* bqk = (float*)(ws + 80 * MB);

  const int M = 4096;  // S*B tokens (b-major everywhere in ws)

  // all converts + x-permute + bias concat in one launch
  cvt_all<<<16386, 256, 0, stream>>>(x, xbf, Wq, Wk, wqkb, Wv, wvb, Wo, wob,
                                     W1, w1b, W2, w2b, bq, bk, bqk);

  // fused Q,K projection: [tok][2048]
  gemm_bt<0, false><<<(M / BM) * (2048 / BN), 256, 0, stream>>>(xbf, wqkb, bqk, nullptr, qkbuf, M, 2048, 1024);
  // V^T projection: C^T = Wv * X^T -> [1024 e][4096 tok], bias by row(e)
  gemm_bt<0, true><<<(1024 / BM) * (M / BN), 256, 0, stream>>>(wvb, xbf, bv, nullptr, vbufT, 1024, M, 1024);

  // attention
  attn_kernel<<<dim3(32, 32), 256, 0, stream>>>(qkbuf, vbufT, aobf);

  // output projection (f32 out)
  gemm_bt<1, false><<<(M / BM) * (1024 / BN), 256, 0, stream>>>(aobf, wob, bo, of32, nullptr, M, 1024, 1024);

  // LN1: x(remapped read) + attn_out -> xn (f32) + xnbf (bf16), b-major
  ln_res<true, true, false><<<4096, 256, 0, stream>>>(x, of32, g1, be1, xn, xnbf);

  // FFN
  gemm_bt<2, false><<<(M / BM) * (4096 / BN), 256, 0, stream>>>(xnbf, w1b, b1, nullptr, y1, M, 4096, 1024);
  gemm_bt<1, false><<<(M / BM) * (1024 / BN), 256, 0, stream>>>(y1, w2b, b2, y2, nullptr, M, 1024, 4096);

  // LN2: xn + y2 -> d_out (remapped write to [S,B,D])
  ln_res<false, false, true><<<4096, 256, 0, stream>>>(xn, y2, g2, be2, (float*)d_out, nullptr);
}